// Round 12
// baseline (1971.255 us; speedup 1.0000x reference)
//
#include <hip/hip_runtime.h>
#include <hip/hip_bf16.h>

#define BB 256      // batch
#define TT 2048     // timesteps
#define DD 32       // obs dim
#define HH 64       // hidden
#define GG 256      // 4*H gates
#define ME 16       // batch elements per block (= MFMA M)
#define NBLK (BB/ME)
#define HSTR 72     // h row stride in u16 (144 B) -> 2-way banks max

typedef short bf16x8 __attribute__((ext_vector_type(8)));
typedef float f32x4 __attribute__((ext_vector_type(4)));

__device__ __forceinline__ float fast_sig(float x) {
    return __builtin_amdgcn_rcpf(1.0f + __expf(-x));
}
__device__ __forceinline__ void split_bf16(float v, unsigned short& hi, unsigned short& lo) {
    unsigned u = __float_as_uint(v);
    hi = (unsigned short)(u >> 16);
    float r = v - __uint_as_float((unsigned)hi << 16);
    lo = (unsigned short)(__float_as_uint(r) >> 16);
}
// split 8 floats (two float4) into hi/lo bf16x8 fragments
__device__ __forceinline__ void split8(float4 a, float4 b, bf16x8& xh, bf16x8& xl) {
    float v[8] = {a.x, a.y, a.z, a.w, b.x, b.y, b.z, b.w};
#pragma unroll
    for (int i = 0; i < 8; ++i) {
        unsigned short hi_, lo_;
        split_bf16(v[i], hi_, lo_);
        xh[i] = (short)hi_;
        xl[i] = (short)lo_;
    }
}
// LDS-only barrier: drain lgkmcnt, leave global loads/stores in flight.
__device__ __forceinline__ void lds_barrier() {
    asm volatile("s_waitcnt lgkmcnt(0)" ::: "memory");
    __builtin_amdgcn_s_barrier();
    asm volatile("" ::: "memory");
}

#define MFMA(A, B_, C_) __builtin_amdgcn_mfma_f32_16x16x32_bf16((A), (B_), (C_), 0, 0, 0)

// 16 elements/block; gates[16,256] = [x|h][16,96] @ W[96,256], bf16 hi/lo split.
// Wave w owns N-tiles {w,4w..}: unit u's i,f,g,o land in the SAME lane.
// x path: global->reg A-frags, split+x-MFMA run one step ahead in the shadow;
// only h crosses LDS (padded rows, 2-way banks). 12 term-accs, depth-2 chains.
__global__ __launch_bounds__(256, 1) void lstm_mfma2_kernel(
    const float* __restrict__ y,    // [B, T, D]
    const float* __restrict__ Wx,   // [D, 4H]
    const float* __restrict__ Wh,   // [H, 4H]
    const float* __restrict__ b,    // [4H]
    float* __restrict__ out)        // [B, T, H]
{
    const int tid = threadIdx.x;
    const int w = tid >> 6;          // wave id 0..3 (N-tile group)
    const int l = tid & 63;
    const int eps = l & 15;          // A-row (element) / B-col lane coord
    const int q = l >> 4;            // k-group lane coord

    __shared__ __align__(16) unsigned short h_hi[2][ME][HSTR];
    __shared__ __align__(16) unsigned short h_lo[2][ME][HSTR];

    // ---- B fragments (hi/lo), loaded once. k<32 -> Wx row k; else Wh row k-32.
    bf16x8 bh[4][3], bl[4][3];
#pragma unroll
    for (int g = 0; g < 4; ++g) {
        const int n = 64 * g + 16 * w + eps;
#pragma unroll
        for (int kc = 0; kc < 3; ++kc) {
#pragma unroll
            for (int s = 0; s < 8; ++s) {
                const int k = 32 * kc + 8 * q + s;
                float v = (k < DD) ? Wx[k * GG + n] : Wh[(k - DD) * GG + n];
                unsigned short hi_, lo_;
                split_bf16(v, hi_, lo_);
                bh[g][kc][s] = (short)hi_;
                bl[g][kc][s] = (short)lo_;
            }
        }
    }
    float bias[4];
#pragma unroll
    for (int g = 0; g < 4; ++g) bias[g] = b[64 * g + 16 * w + eps];

    float cr[4] = {0.0f, 0.0f, 0.0f, 0.0f};   // c for elements e=4q+r

    // zero both h buffers (h0 = 0)
    for (int i = tid; i < 2 * ME * HSTR; i += 256) {
        ((unsigned short*)h_hi)[i] = 0;
        ((unsigned short*)h_lo)[i] = 0;
    }

    // per-lane x source: element eps of this block, k-slice 8q
    const float* ybase = y + ((size_t)(blockIdx.x * ME + eps) * TT) * DD + 8 * q;
    float* ob = out + (size_t)(blockIdx.x * ME) * TT * HH;

    const f32x4 Z = {0.0f, 0.0f, 0.0f, 0.0f};
    f32x4 am[4], ar[4], as_[4];    // main / A-residual / B-residual accs

    // ---- prologue: x(0) -> x-MFMA into accs; x(1) -> pair P1
    float4 f10, f11, f00 = {0,0,0,0}, f01 = {0,0,0,0};
    {
        const float4* p0 = (const float4*)ybase;
        float4 a0 = p0[0], a1 = p0[1];
        const float4* p1 = (const float4*)(ybase + DD);
        f10 = p1[0]; f11 = p1[1];
        bf16x8 xh, xl;
        split8(a0, a1, xh, xl);
#pragma unroll
        for (int g = 0; g < 4; ++g) {
            am[g] = MFMA(xh, bh[g][0], Z);
            ar[g] = MFMA(xl, bh[g][0], Z);
            as_[g] = MFMA(xh, bl[g][0], Z);
        }
    }
    __syncthreads();

    // STEPX: consume FC (x(T+1) f32), load x(T+2) into FN.
#define STEPX(T, RD, FC0, FC1, FN0, FN1)                                       \
    {                                                                          \
        /* issue next-next x load; consumed next iter (~full step of lead) */  \
        const int tn_ = ((T) + 2 < TT) ? ((T) + 2) : (TT - 1);                 \
        const float4* np_ = (const float4*)(ybase + (size_t)tn_ * DD);         \
        FN0 = np_[0]; FN1 = np_[1];                                            \
        /* h A-fragments (padded rows: 2-way banks worst) */                   \
        bf16x8 hh1 = *(const bf16x8*)&h_hi[RD][eps][8 * q];                    \
        bf16x8 hl1 = *(const bf16x8*)&h_lo[RD][eps][8 * q];                    \
        bf16x8 hh2 = *(const bf16x8*)&h_hi[RD][eps][32 + 8 * q];               \
        bf16x8 hl2 = *(const bf16x8*)&h_lo[RD][eps][32 + 8 * q];               \
        /* h-MFMAs: 12 chains, depth 2 */                                      \
        _Pragma("unroll")                                                      \
        for (int g = 0; g < 4; ++g) {                                          \
            am[g] = MFMA(hh1, bh[g][1], am[g]);                                \
            ar[g] = MFMA(hl1, bh[g][1], ar[g]);                                \
            as_[g] = MFMA(hh1, bl[g][1], as_[g]);                              \
        }                                                                      \
        _Pragma("unroll")                                                      \
        for (int g = 0; g < 4; ++g) {                                          \
            am[g] = MFMA(hh2, bh[g][2], am[g]);                                \
            ar[g] = MFMA(hl2, bh[g][2], ar[g]);                                \
            as_[g] = MFMA(hh2, bl[g][2], as_[g]);                              \
        }                                                                      \
        /* gate pre-activations (SSA reads; accs then re-init by x-MFMA) */    \
        float gv[4][4];                                                        \
        _Pragma("unroll")                                                      \
        for (int g = 0; g < 4; ++g)                                            \
            _Pragma("unroll")                                                  \
            for (int r = 0; r < 4; ++r)                                        \
                gv[g][r] = ((am[g][r] + ar[g][r]) + as_[g][r]) + bias[g];      \
        /* x-MFMAs for step T+1 (off the post-act chain) */                    \
        {                                                                      \
            bf16x8 xh_, xl_;                                                   \
            split8(FC0, FC1, xh_, xl_);                                        \
            _Pragma("unroll")                                                  \
            for (int g = 0; g < 4; ++g) {                                      \
                am[g] = MFMA(xh_, bh[g][0], Z);                                \
                ar[g] = MFMA(xl_, bh[g][0], Z);                                \
                as_[g] = MFMA(xh_, bl[g][0], Z);                               \
            }                                                                  \
        }                                                                      \
        /* activations + state update + h publish */                           \
        _Pragma("unroll")                                                      \
        for (int r = 0; r < 4; ++r) {                                          \
            float i_ = fast_sig(gv[0][r]);                                     \
            float f_ = fast_sig(gv[1][r]);                                     \
            float g_ = fmaf(2.0f, fast_sig(2.0f * gv[2][r]), -1.0f);           \
            float o_ = fast_sig(gv[3][r]);                                     \
            cr[r] = fmaf(f_, cr[r], i_ * g_);                                  \
            float h_ = o_ * fmaf(2.0f, fast_sig(2.0f * cr[r]), -1.0f);         \
            unsigned short hh_, hl_;                                           \
            split_bf16(h_, hh_, hl_);                                          \
            const int e_ = 4 * q + r;                                          \
            h_hi[(RD) ^ 1][e_][16 * w + eps] = hh_;                            \
            h_lo[(RD) ^ 1][e_][16 * w + eps] = hl_;                            \
            ob[((size_t)e_ * TT + (T)) * HH + 16 * w + eps] = h_;              \
        }                                                                      \
        lds_barrier();                                                         \
    }

    for (int t = 0; t < TT; t += 2) {
        STEPX(t,     0, f10, f11, f00, f01)   // consume x(t+1)=P1, load x(t+2)->P0
        STEPX(t + 1, 1, f00, f01, f10, f11)   // consume x(t+2)=P0, load x(t+3)->P1
    }
#undef STEPX
}

extern "C" void kernel_launch(void* const* d_in, const int* in_sizes, int n_in,
                              void* d_out, int out_size, void* d_ws, size_t ws_size,
                              hipStream_t stream) {
    const float* y  = (const float*)d_in[0];
    const float* Wx = (const float*)d_in[1];
    const float* Wh = (const float*)d_in[2];
    const float* b  = (const float*)d_in[3];
    float* out = (float*)d_out;

    lstm_mfma2_kernel<<<NBLK, 256, 0, stream>>>(y, Wx, Wh, b, out);
}

// Round 13
// 1289.968 us; speedup vs baseline: 1.5281x; 1.5281x over previous
//
#include <hip/hip_runtime.h>

#define BB 256      // batch
#define TT 2048     // timesteps
#define DD 32       // obs dim
#define HH 64       // hidden
#define GG 256      // 4*H gates
#define OB 16       // steps per output burst

__device__ __forceinline__ float fast_sig(float x) {
    return __builtin_amdgcn_rcpf(1.0f + __expf(-x));
}
__device__ __forceinline__ float rdlane(float v, int k) {
    return __uint_as_float(__builtin_amdgcn_readlane(__float_as_uint(v), k));
}
// LDS-only barrier: drain lgkmcnt, leave global loads/stores in flight.
__device__ __forceinline__ void lds_barrier() {
    asm volatile("s_waitcnt lgkmcnt(0)" ::: "memory");
    __builtin_amdgcn_s_barrier();
    asm volatile("" ::: "memory");
}

// R4 structure (4 waves = 4 gate types, readlane h-broadcast, replicated
// c/h update) with a VMEM-wait-free steady-state loop:
//  - x-FMAs consume the current x registers BEFORE the next-x prefetch is
//    issued, so any vmcnt wait covers only loads issued a full step ago.
//  - h is staged in an LDS ring and written to HBM as one coalesced
//    float4 burst per 16 steps -> no global stores inside steady steps.
__global__ __launch_bounds__(256, 1) void lstm_burst_kernel(
    const float* __restrict__ y,    // [B, T, D]
    const float* __restrict__ Wx,   // [D, 4H]
    const float* __restrict__ Wh,   // [H, 4H]
    const float* __restrict__ b,    // [4H]
    float* __restrict__ out)        // [B, T, H]
{
    const int j = threadIdx.x;        // gate column 0..255
    const int w = j >> 6;             // wave id = gate type (0=i,1=f,2=g,3=o)
    const int l = j & 63;             // lane = hidden unit
    const int batch = blockIdx.x;

    __shared__ float gbuf[2][4][HH];      // activated-gate exchange (dbuf)
    __shared__ float obuf[2][OB][HH];     // output staging ring (dbuf, 8 KB)

    // weight columns in registers (coalesced: fixed k, consecutive j)
    float wx[DD];
#pragma unroll
    for (int k = 0; k < DD; ++k) wx[k] = Wx[k * GG + j];
    float wh[HH];
#pragma unroll
    for (int k = 0; k < HH; ++k) wh[k] = Wh[k * GG + j];
    const float bj = b[j];

    // wave-uniform activation: sigmoid for i,f,o; tanh(x)=2*sig(2x)-1 for g
    const bool isg = (w == 2);
    const float sc = isg ? 2.0f : 1.0f;
    const float aa = isg ? 2.0f : 1.0f;
    const float ab = isg ? -1.0f : 0.0f;

    float c = 0.0f, h = 0.0f;         // lane l's replica of c[l], h[l]

    const float* ybase = y + (size_t)batch * (TT * DD);
    float* obase = out + (size_t)batch * (TT * HH);

    // x row double-buffered in registers
    float4 xa[DD / 4], xb[DD / 4];
    {
        const float4* r0 = (const float4*)ybase;
#pragma unroll
        for (int q = 0; q < DD / 4; ++q) xa[q] = r0[q];
    }

    __syncthreads();   // once at init

    // XC: current x row (consumed FIRST); XN: prefetch target (issued AFTER).
#define STEP(XC, XN, BUFI, TI, TL)                                             \
    {                                                                          \
        /* x part: consume XC before any new VMEM is issued */                 \
        float ac0 = bj, ac1 = 0.0f, ac2 = 0.0f, ac3 = 0.0f;                    \
        _Pragma("unroll")                                                      \
        for (int q = 0; q < DD / 4; ++q) {                                     \
            ac0 = fmaf(XC[q].x, wx[4 * q + 0], ac0);                           \
            ac1 = fmaf(XC[q].y, wx[4 * q + 1], ac1);                           \
            ac2 = fmaf(XC[q].z, wx[4 * q + 2], ac2);                           \
            ac3 = fmaf(XC[q].w, wx[4 * q + 3], ac3);                           \
        }                                                                      \
        /* now issue next-x prefetch; consumed only next step */               \
        const int tn_ = ((TI) + 1 < TT) ? ((TI) + 1) : (TT - 1);               \
        const float4* nrow_ = (const float4*)(ybase + (size_t)tn_ * DD);       \
        _Pragma("unroll")                                                      \
        for (int q = 0; q < DD / 4; ++q) XN[q] = nrow_[q];                     \
        /* h part: readlane broadcast, zero LDS */                             \
        _Pragma("unroll")                                                      \
        for (int k4 = 0; k4 < HH / 4; ++k4) {                                  \
            ac0 = fmaf(rdlane(h, 4 * k4 + 0), wh[4 * k4 + 0], ac0);            \
            ac1 = fmaf(rdlane(h, 4 * k4 + 1), wh[4 * k4 + 1], ac1);            \
            ac2 = fmaf(rdlane(h, 4 * k4 + 2), wh[4 * k4 + 2], ac2);            \
            ac3 = fmaf(rdlane(h, 4 * k4 + 3), wh[4 * k4 + 3], ac3);            \
        }                                                                      \
        float g_ = (ac0 + ac1) + (ac2 + ac3);                                  \
        gbuf[BUFI][w][l] = fmaf(aa, fast_sig(sc * g_), ab);                    \
        lds_barrier();                                                         \
        float ig_ = gbuf[BUFI][0][l];                                          \
        float fg_ = gbuf[BUFI][1][l];                                          \
        float gg_ = gbuf[BUFI][2][l];                                          \
        float og_ = gbuf[BUFI][3][l];                                          \
        c = fmaf(fg_, c, ig_ * gg_);                                           \
        h = og_ * fmaf(2.0f, fast_sig(2.0f * c), -1.0f);   /* o*tanh(c) */     \
        if (w == 0) obuf[obi][TL][l] = h;        /* LDS, not HBM */            \
    }

    for (int t0 = 0; t0 < TT; t0 += OB) {
        const int obi = (t0 >> 4) & 1;
#pragma unroll
        for (int tp = 0; tp < OB; tp += 2) {
            STEP(xa, xb, 0, t0 + tp, tp)
            STEP(xb, xa, 1, t0 + tp + 1, tp + 1)
        }
        // publish w0's obuf rows to all waves, then burst-store coalesced.
        lds_barrier();
        {
            const int r = j >> 4;              // row 0..15
            const int ci = (j & 15) * 4;       // col 0..60
            const float4 v = *(const float4*)&obuf[obi][r][ci];
            *(float4*)&obase[(size_t)(t0 + r) * HH + ci] = v;
            // store stays in flight; nothing ever waits on it (obuf dbuf'd)
        }
    }
#undef STEP
}

extern "C" void kernel_launch(void* const* d_in, const int* in_sizes, int n_in,
                              void* d_out, int out_size, void* d_ws, size_t ws_size,
                              hipStream_t stream) {
    const float* y  = (const float*)d_in[0];
    const float* Wx = (const float*)d_in[1];
    const float* Wh = (const float*)d_in[2];
    const float* b  = (const float*)d_in[3];
    float* out = (float*)d_out;

    lstm_burst_kernel<<<BB, GG, 0, stream>>>(y, Wx, Wh, b, out);
}

// Round 14
// 1242.375 us; speedup vs baseline: 1.5867x; 1.0383x over previous
//
#include <hip/hip_runtime.h>

#define BB 256      // batch
#define TT 2048     // timesteps
#define DD 32       // obs dim
#define HH 64       // hidden
#define GG 256      // 4*H gates
#define OB 8        // steps per output burst

__device__ __forceinline__ float fast_sig(float x) {
    return __builtin_amdgcn_rcpf(1.0f + __expf(-x));
}
__device__ __forceinline__ float rdlane(float v, int k) {
    return __uint_as_float(__builtin_amdgcn_readlane(__float_as_uint(v), k));
}
// LDS-only barrier: drain lgkmcnt, leave global loads/stores in flight.
__device__ __forceinline__ void lds_barrier() {
    asm volatile("s_waitcnt lgkmcnt(0)" ::: "memory");
    __builtin_amdgcn_s_barrier();
    asm volatile("" ::: "memory");
}

// R12 structure (4 gate-waves, rdlane h-GEMV, replicated update, burst
// stores) with the x-part LIFTED OUT of the serial chain: accumulators are
// carried across steps, pre-initialized to bias + x(t+1)*Wx inside step t's
// exchange shadows (write-ack window and read-latency window). Each step
// begins directly with the h-GEMV -- the true head of the recurrence chain.
__global__ __launch_bounds__(256, 1) void lstm_shadow_kernel(
    const float* __restrict__ y,    // [B, T, D]
    const float* __restrict__ Wx,   // [D, 4H]
    const float* __restrict__ Wh,   // [H, 4H]
    const float* __restrict__ b,    // [4H]
    float* __restrict__ out)        // [B, T, H]
{
    const int j = threadIdx.x;        // gate column 0..255
    const int w = j >> 6;             // wave id = gate type (0=i,1=f,2=g,3=o)
    const int l = j & 63;             // lane = hidden unit
    const int batch = blockIdx.x;

    __shared__ float gbuf[2][4][HH];      // activated-gate exchange (dbuf)
    __shared__ float obuf[2][OB][HH];     // output staging ring (dbuf, 4 KB)

    // weight columns in registers (coalesced: fixed k, consecutive j)
    float wx[DD];
#pragma unroll
    for (int k = 0; k < DD; ++k) wx[k] = Wx[k * GG + j];
    float wh[HH];
#pragma unroll
    for (int k = 0; k < HH; ++k) wh[k] = Wh[k * GG + j];
    const float bj = b[j];

    // wave-uniform activation: sigmoid for i,f,o; tanh(x)=2*sig(2x)-1 for g
    const bool isg = (w == 2);
    const float sc = isg ? 2.0f : 1.0f;
    const float aa = isg ? 2.0f : 1.0f;
    const float ab = isg ? -1.0f : 0.0f;

    float c = 0.0f, h = 0.0f;         // lane l's replica of c[l], h[l]

    const float* ybase = y + (size_t)batch * (TT * DD);
    float* obase = out + (size_t)batch * (TT * HH);

    // x rows double-buffered in registers; accumulators carried across steps
    float4 xa[DD / 4], xb[DD / 4];
    float ac0, ac1, ac2, ac3;
    {
        // acc <- bias + x(0)*Wx ; xa <- x(1)
        const float4* r0 = (const float4*)ybase;
        float4 x0[DD / 4];
#pragma unroll
        for (int q = 0; q < DD / 4; ++q) x0[q] = r0[q];
        ac0 = bj; ac1 = 0.0f; ac2 = 0.0f; ac3 = 0.0f;
#pragma unroll
        for (int q = 0; q < DD / 4; ++q) {
            ac0 = fmaf(x0[q].x, wx[4 * q + 0], ac0);
            ac1 = fmaf(x0[q].y, wx[4 * q + 1], ac1);
            ac2 = fmaf(x0[q].z, wx[4 * q + 2], ac2);
            ac3 = fmaf(x0[q].w, wx[4 * q + 3], ac3);
        }
        const float4* r1 = (const float4*)(ybase + DD);
#pragma unroll
        for (int q = 0; q < DD / 4; ++q) xa[q] = r1[q];
    }
    __syncthreads();   // once at init

    // XC: x(TI+1) regs (consumed in the shadows); XN: prefetch tgt x(TI+2).
#define STEP(XC, XN, BUFI, TI, TL)                                            \
    {                                                                         \
        /* 1. chain head: h-GEMV accumulates into carried accs */             \
        _Pragma("unroll")                                                     \
        for (int k4 = 0; k4 < HH / 4; ++k4) {                                 \
            ac0 = fmaf(rdlane(h, 4 * k4 + 0), wh[4 * k4 + 0], ac0);           \
            ac1 = fmaf(rdlane(h, 4 * k4 + 1), wh[4 * k4 + 1], ac1);           \
            ac2 = fmaf(rdlane(h, 4 * k4 + 2), wh[4 * k4 + 2], ac2);           \
            ac3 = fmaf(rdlane(h, 4 * k4 + 3), wh[4 * k4 + 3], ac3);           \
        }                                                                     \
        float g_ = (ac0 + ac1) + (ac2 + ac3);                                 \
        gbuf[BUFI][w][l] = fmaf(aa, fast_sig(sc * g_), ab);                   \
        /* 2. shadow-a: re-init accs with bias + x(TI+1) quads 0..5 --       \
              issues during the gbuf write-ack the lgkmcnt(0) waits on */     \
        ac0 = bj; ac1 = 0.0f; ac2 = 0.0f; ac3 = 0.0f;                         \
        _Pragma("unroll")                                                     \
        for (int q = 0; q < 6; ++q) {                                         \
            ac0 = fmaf(XC[q].x, wx[4 * q + 0], ac0);                          \
            ac1 = fmaf(XC[q].y, wx[4 * q + 1], ac1);                          \
            ac2 = fmaf(XC[q].z, wx[4 * q + 2], ac2);                          \
            ac3 = fmaf(XC[q].w, wx[4 * q + 3], ac3);                          \
        }                                                                     \
        lds_barrier();                                                        \
        /* 3. gate reads issue; shadow-b + prefetch fill their latency */     \
        float ig_ = gbuf[BUFI][0][l];                                         \
        float fg_ = gbuf[BUFI][1][l];                                         \
        float gg_ = gbuf[BUFI][2][l];                                         \
        float og_ = gbuf[BUFI][3][l];                                         \
        _Pragma("unroll")                                                     \
        for (int q = 6; q < 8; ++q) {                                         \
            ac0 = fmaf(XC[q].x, wx[4 * q + 0], ac0);                          \
            ac1 = fmaf(XC[q].y, wx[4 * q + 1], ac1);                          \
            ac2 = fmaf(XC[q].z, wx[4 * q + 2], ac2);                          \
            ac3 = fmaf(XC[q].w, wx[4 * q + 3], ac3);                          \
        }                                                                     \
        {                                                                     \
            const int tn_ = ((TI) + 2 < TT) ? ((TI) + 2) : (TT - 1);          \
            const float4* nrow_ = (const float4*)(ybase + (size_t)tn_ * DD);  \
            _Pragma("unroll")                                                 \
            for (int q = 0; q < DD / 4; ++q) XN[q] = nrow_[q];                \
        }                                                                     \
        /* 4. update */                                                       \
        c = fmaf(fg_, c, ig_ * gg_);                                          \
        h = og_ * fmaf(2.0f, fast_sig(2.0f * c), -1.0f);   /* o*tanh(c) */    \
        if (w == 0) obuf[obi][TL][l] = h;                                     \
    }

    for (int t0 = 0; t0 < TT; t0 += OB) {
        const int obi = (t0 >> 3) & 1;
#pragma unroll
        for (int tp = 0; tp < OB; tp += 2) {
            STEP(xa, xb, 0, t0 + tp, tp)
            STEP(xb, xa, 1, t0 + tp + 1, tp + 1)
        }
        // publish w0's obuf rows, then coalesced burst store (fire & forget)
        lds_barrier();
        {
            const int r = j >> 5;              // row 0..7
            const int ci = (j & 31) * 2;       // col 0..62
            const float2 v = *(const float2*)&obuf[obi][r][ci];
            *(float2*)&obase[(size_t)(t0 + r) * HH + ci] = v;
        }
    }
#undef STEP
}

extern "C" void kernel_launch(void* const* d_in, const int* in_sizes, int n_in,
                              void* d_out, int out_size, void* d_ws, size_t ws_size,
                              hipStream_t stream) {
    const float* y  = (const float*)d_in[0];
    const float* Wx = (const float*)d_in[1];
    const float* Wh = (const float*)d_in[2];
    const float* b  = (const float*)d_in[3];
    float* out = (float*)d_out;

    lstm_shadow_kernel<<<BB, GG, 0, stream>>>(y, Wx, Wh, b, out);
}

// Round 15
// 961.250 us; speedup vs baseline: 2.0507x; 1.2925x over previous
//
#include <hip/hip_runtime.h>

#define BB 256      // batch
#define TT 2048     // timesteps
#define DD 32       // obs dim
#define HH 64       // hidden
#define GG 256      // 4*H gates
#define OB 8        // steps per output burst

__device__ __forceinline__ float fast_sig(float x) {
    return __builtin_amdgcn_rcpf(1.0f + __expf(-x));
}
__device__ __forceinline__ float rdlane(float v, int k) {
    return __uint_as_float(__builtin_amdgcn_readlane(__float_as_uint(v), k));
}
// LDS-only barrier: drain lgkmcnt, leave global loads/stores in flight.
__device__ __forceinline__ void lds_barrier() {
    asm volatile("s_waitcnt lgkmcnt(0)" ::: "memory");
    __builtin_amdgcn_s_barrier();
    asm volatile("" ::: "memory");
}

// K-SPLIT structure: wave w computes, for ALL 4 gates of unit l, the
// partial pre-activation sum over its K-slice (x[8w..8w+8), h[16w..16w+16)).
// Exchange = pre-activation partials: 1 ds_write_b128 + 4 ds_read_b128.
// GEMV on the chain is only 16 rdlane + 64 FMA (each broadcast feeds 4
// gates). All 4 activations run ILP-parallel AFTER the read. h/c stay
// in-register replicas (every wave reconstructs them identically).
__global__ __launch_bounds__(256, 1) void lstm_ksplit_kernel(
    const float* __restrict__ y,    // [B, T, D]
    const float* __restrict__ Wx,   // [D, 4H]
    const float* __restrict__ Wh,   // [H, 4H]
    const float* __restrict__ b,    // [4H]
    float* __restrict__ out)        // [B, T, H]
{
    const int j = threadIdx.x;        // 0..255
    const int w = j >> 6;             // wave id = K-slice 0..3
    const int l = j & 63;             // lane = hidden unit
    const int batch = blockIdx.x;
    const int kb = 16 * w;            // h K-slice base

    __shared__ float4 gbuf[2][4][HH];     // [buf][wave][unit] partials (8 KB)
    __shared__ float obuf[2][OB][HH];     // output staging ring (4 KB)

    // ---- per-lane weight slices (coalesced: fixed row, lanes consecutive)
    float wh[4][16];                  // Wh rows kb..kb+15, cols g*64+l
#pragma unroll
    for (int g = 0; g < 4; ++g)
#pragma unroll
        for (int k = 0; k < 16; ++k)
            wh[g][k] = Wh[(kb + k) * GG + g * HH + l];
    float wx[4][8];                   // Wx rows 8w..8w+7, cols g*64+l
#pragma unroll
    for (int g = 0; g < 4; ++g)
#pragma unroll
        for (int d = 0; d < 8; ++d)
            wx[g][d] = Wx[(8 * w + d) * GG + g * HH + l];
    float bj[4];                      // bias: only wave 0 carries it
#pragma unroll
    for (int g = 0; g < 4; ++g) bj[g] = (w == 0) ? b[g * HH + l] : 0.0f;

    float c = 0.0f, h = 0.0f;         // lane l's replica of c[l], h[l]

    const float* ybase = y + (size_t)batch * (TT * DD) + 8 * w;
    float* obase = out + (size_t)batch * (TT * HH);

    // x slice (8 floats) double-buffered; accumulators carried across steps
    float4 xa[2], xb[2];
    float a0[4], a1[4];
    {
        // a <- bias + x(0)*Wx ; xa <- x(1)
        const float4* r0 = (const float4*)ybase;
        float4 x00 = r0[0], x01 = r0[1];
        const float* xf = (const float*)&x00;
        const float* xg = (const float*)&x01;
#pragma unroll
        for (int g = 0; g < 4; ++g) { a0[g] = bj[g]; a1[g] = 0.0f; }
#pragma unroll
        for (int d = 0; d < 4; ++d)
#pragma unroll
            for (int g = 0; g < 4; ++g) a0[g] = fmaf(xf[d], wx[g][d], a0[g]);
#pragma unroll
        for (int d = 0; d < 4; ++d)
#pragma unroll
            for (int g = 0; g < 4; ++g) a1[g] = fmaf(xg[d], wx[g][d + 4], a1[g]);
        const float4* r1 = (const float4*)(ybase + DD);
        xa[0] = r1[0]; xa[1] = r1[1];
    }
    __syncthreads();   // once at init

    // XC: x(TI+1) regs (consumed in shadows); XN: prefetch target x(TI+2).
#define STEP(XC, XN, BUFI, TI, TL)                                            \
    {                                                                         \
        /* 1. chain head: h-GEMV, 16 rdlane each feeding 4 gates */           \
        _Pragma("unroll")                                                     \
        for (int k = 0; k < 8; ++k) {                                         \
            const float hk = rdlane(h, kb + k);                               \
            _Pragma("unroll")                                                 \
            for (int g = 0; g < 4; ++g) a0[g] = fmaf(hk, wh[g][k], a0[g]);    \
        }                                                                     \
        _Pragma("unroll")                                                     \
        for (int k = 8; k < 16; ++k) {                                        \
            const float hk = rdlane(h, kb + k);                               \
            _Pragma("unroll")                                                 \
            for (int g = 0; g < 4; ++g) a1[g] = fmaf(hk, wh[g][k], a1[g]);    \
        }                                                                     \
        /* 2. fold + publish partials (single b128, 2-way banks = free) */    \
        float4 pw;                                                            \
        pw.x = a0[0] + a1[0]; pw.y = a0[1] + a1[1];                           \
        pw.z = a0[2] + a1[2]; pw.w = a0[3] + a1[3];                           \
        gbuf[BUFI][w][l] = pw;                                                \
        /* 3. shadow-a (covers write-ack): acc re-init + x d0..3, then       \
              issue next-x prefetch (long lead, consumed next step) */        \
        {                                                                     \
            const float* xf_ = (const float*)&XC[0];                          \
            _Pragma("unroll")                                                 \
            for (int g = 0; g < 4; ++g) a0[g] = bj[g];                        \
            _Pragma("unroll")                                                 \
            for (int d = 0; d < 4; ++d)                                       \
                _Pragma("unroll")                                             \
                for (int g = 0; g < 4; ++g)                                   \
                    a0[g] = fmaf(xf_[d], wx[g][d], a0[g]);                    \
        }                                                                     \
        {                                                                     \
            const int tn_ = ((TI) + 2 < TT) ? ((TI) + 2) : (TT - 1);          \
            const float4* nr_ = (const float4*)(ybase + (size_t)tn_ * DD);    \
            XN[0] = nr_[0]; XN[1] = nr_[1];                                   \
        }                                                                     \
        lds_barrier();                                                        \
        /* 4. reads issue; shadow-b (x d4..7) fills their latency */          \
        const float4 P0 = gbuf[BUFI][0][l];                                   \
        const float4 P1 = gbuf[BUFI][1][l];                                   \
        const float4 P2 = gbuf[BUFI][2][l];                                   \
        const float4 P3 = gbuf[BUFI][3][l];                                   \
        {                                                                     \
            const float* xg_ = (const float*)&XC[1];                          \
            _Pragma("unroll")                                                 \
            for (int g = 0; g < 4; ++g) a1[g] = 0.0f;                         \
            _Pragma("unroll")                                                 \
            for (int d = 0; d < 4; ++d)                                       \
                _Pragma("unroll")                                             \
                for (int g = 0; g < 4; ++g)                                   \
                    a1[g] = fmaf(xg_[d], wx[g][d + 4], a1[g]);                \
        }                                                                     \
        /* 5. sum partials; 4 activation chains run ILP-parallel */           \
        const float gi_ = (P0.x + P1.x) + (P2.x + P3.x);                      \
        const float gf_ = (P0.y + P1.y) + (P2.y + P3.y);                      \
        const float gg_ = (P0.z + P1.z) + (P2.z + P3.z);                      \
        const float go_ = (P0.w + P1.w) + (P2.w + P3.w);                      \
        const float i_ = fast_sig(gi_);                                       \
        const float f_ = fast_sig(gf_);                                       \
        const float g_ = fmaf(2.0f, fast_sig(2.0f * gg_), -1.0f);             \
        const float o_ = fast_sig(go_);                                       \
        c = fmaf(f_, c, i_ * g_);                                             \
        h = o_ * fmaf(2.0f, fast_sig(2.0f * c), -1.0f);   /* o*tanh(c) */     \
        if (w == 0) obuf[obi][TL][l] = h;                                     \
    }

    for (int t0 = 0; t0 < TT; t0 += OB) {
        const int obi = (t0 >> 3) & 1;
#pragma unroll
        for (int tp = 0; tp < OB; tp += 2) {
            STEP(xa, xb, 0, t0 + tp, tp)
            STEP(xb, xa, 1, t0 + tp + 1, tp + 1)
        }
        // publish w0's obuf rows, then coalesced burst store (fire & forget)
        lds_barrier();
        {
            const int r = j >> 5;              // row 0..7
            const int ci = (j & 31) * 2;       // col 0..62
            const float2 v = *(const float2*)&obuf[obi][r][ci];
            *(float2*)&obase[(size_t)(t0 + r) * HH + ci] = v;
        }
    }
#undef STEP
}

extern "C" void kernel_launch(void* const* d_in, const int* in_sizes, int n_in,
                              void* d_out, int out_size, void* d_ws, size_t ws_size,
                              hipStream_t stream) {
    const float* y  = (const float*)d_in[0];
    const float* Wx = (const float*)d_in[1];
    const float* Wh = (const float*)d_in[2];
    const float* b  = (const float*)d_in[3];
    float* out = (float*)d_out;

    lstm_ksplit_kernel<<<BB, GG, 0, stream>>>(y, Wx, Wh, b, out);
}